// Round 1
// baseline (363.940 us; speedup 1.0000x reference)
//
#include <hip/hip_runtime.h>

typedef __bf16 bf16x8 __attribute__((ext_vector_type(8)));
typedef float f32x4 __attribute__((ext_vector_type(4)));

#define AS1 __attribute__((address_space(1)))
#define AS3 __attribute__((address_space(3)))

// RNE fp32 -> bf16 bits (inputs are finite; no NaN handling needed)
static __device__ __forceinline__ unsigned short f2bf(float f) {
  unsigned int u = __float_as_uint(f);
  u += 0x7FFFu + ((u >> 16) & 1u);
  return (unsigned short)(u >> 16);
}

__global__ void cvt_x_kernel(const float4* __restrict__ in,
                             ushort4* __restrict__ out, int n4) {
  int i = blockIdx.x * blockDim.x + threadIdx.x;
  if (i >= n4) return;
  float4 v = in[i];
  ushort4 o;
  o.x = f2bf(v.x); o.y = f2bf(v.y); o.z = f2bf(v.z); o.w = f2bf(v.w);
  out[i] = o;
}

__global__ void cvt_w_kernel(const int4* __restrict__ in,
                             ushort4* __restrict__ out, int n4) {
  int i = blockIdx.x * blockDim.x + threadIdx.x;
  if (i >= n4) return;
  int4 v = in[i];
  ushort4 o;
  // int8-range integers are exact in bf16
  o.x = f2bf((float)v.x); o.y = f2bf((float)v.y);
  o.z = f2bf((float)v.z); o.w = f2bf((float)v.w);
  out[i] = o;
}

// C[M][N] = A[M][K] * B[N][K]^T * scaler[N]   (all bf16 inputs, fp32 acc/out)
// m97 structure: 128x128 tile, BK=32, 4 waves, 4x4 16x16x32 MFMA per wave,
// global_load_lds width=16 staging (unpadded LDS; wave-uniform base + lane*16).
__global__ __launch_bounds__(256) void gemm_bt_kernel(
    const unsigned short* __restrict__ A,   // [M][K] bf16 bits
    const unsigned short* __restrict__ B,   // [N][K] bf16 bits
    const float* __restrict__ scaler,       // [N]
    float* __restrict__ C,                  // [M][N] fp32
    int M, int N, int K)
{
  __shared__ unsigned short sA[128 * 32];
  __shared__ unsigned short sB[128 * 32];

  const int tid  = threadIdx.x;
  const int wave = tid >> 6;
  const int lane = tid & 63;
  const int bm = blockIdx.y << 7;
  const int bn = blockIdx.x << 7;
  const int wm = (wave >> 1) << 6;   // wave's row offset in tile (2x2 wave grid)
  const int wn = (wave & 1) << 6;
  const int l15  = lane & 15;
  const int quad = lane >> 4;

  // Staging map: round r (0,1), wave w covers LDS bytes [(r*4+w)*1024, +1024).
  // LDS tile is row-major [128][32] bf16 (64 B/row, NO padding — required by
  // global_load_lds lane-ordering). Lane covers row = r*64 + w*16 + lane/4,
  // k-offset = (lane&3)*8.
  const int srow  = wave * 16 + (lane >> 2);
  const int skoff = (lane & 3) * 8;
  const unsigned short* ga = A + (size_t)(bm + srow) * K + skoff;
  const unsigned short* gb = B + (size_t)(bn + srow) * K + skoff;
  const size_t rstep = (size_t)64 * K;      // +64 rows for round 1

  unsigned short* lA = &sA[wave * 512];     // wave-uniform LDS base, round 0
  unsigned short* lB = &sB[wave * 512];

  f32x4 acc[4][4] = {};                     // [mi][ni], 64 VGPR/AGPR

  for (int k0 = 0; k0 < K; k0 += 32) {
    __builtin_amdgcn_global_load_lds((AS1 void*)(ga + k0),         (AS3 void*)lA,           16, 0, 0);
    __builtin_amdgcn_global_load_lds((AS1 void*)(ga + k0 + rstep), (AS3 void*)(lA + 2048),  16, 0, 0);
    __builtin_amdgcn_global_load_lds((AS1 void*)(gb + k0),         (AS3 void*)lB,           16, 0, 0);
    __builtin_amdgcn_global_load_lds((AS1 void*)(gb + k0 + rstep), (AS3 void*)(lB + 2048),  16, 0, 0);
    __syncthreads();   // compiler emits vmcnt(0) drain here — LDS is populated

    // A-frag: lane holds A[m=l15][k=quad*8 + j]; same pattern for B (B^T input)
    bf16x8 av[4], bv[4];
    #pragma unroll
    for (int mi = 0; mi < 4; ++mi) {
      int row = wm + mi * 16 + l15;
      av[mi] = *(const bf16x8*)&sA[row * 32 + quad * 8];
    }
    #pragma unroll
    for (int ni = 0; ni < 4; ++ni) {
      int row = wn + ni * 16 + l15;
      bv[ni] = *(const bf16x8*)&sB[row * 32 + quad * 8];
    }
    #pragma unroll
    for (int mi = 0; mi < 4; ++mi)
      #pragma unroll
      for (int ni = 0; ni < 4; ++ni)
        acc[mi][ni] = __builtin_amdgcn_mfma_f32_16x16x32_bf16(av[mi], bv[ni], acc[mi][ni], 0, 0, 0);
    __syncthreads();   // protect LDS from next iteration's staging
  }

  // Epilogue: C/D layout col = lane&15 (N), row = quad*4 + reg (M). Apply
  // per-output-channel scaler in fp32 (exact).
  #pragma unroll
  for (int ni = 0; ni < 4; ++ni) {
    int gn = bn + wn + ni * 16 + l15;
    float s = scaler[gn];
    #pragma unroll
    for (int mi = 0; mi < 4; ++mi) {
      int gm0 = bm + wm + mi * 16 + quad * 4;
      #pragma unroll
      for (int r = 0; r < 4; ++r)
        C[(size_t)(gm0 + r) * N + gn] = acc[mi][ni][r] * s;
    }
  }
}

extern "C" void kernel_launch(void* const* d_in, const int* in_sizes, int n_in,
                              void* d_out, int out_size, void* d_ws, size_t ws_size,
                              hipStream_t stream) {
  const float* x  = (const float*)d_in[0];          // [B,S,K] fp32
  const int*   w  = (const int*)d_in[1];            // [N,K] int32 (int8 range)
  const float* sc = (const float*)d_in[2];          // [N] fp32
  float* out = (float*)d_out;

  const int N = in_sizes[2];                        // 4096
  const int K = in_sizes[1] / N;                    // 4096
  const int M = in_sizes[0] / K;                    // 4096

  unsigned short* Abf = (unsigned short*)d_ws;              // [M][K] bf16
  unsigned short* Wbf = Abf + (size_t)N * K;                // [N][K] bf16

  int n4x = (M * K) / 4;
  cvt_x_kernel<<<(n4x + 255) / 256, 256, 0, stream>>>((const float4*)x, (ushort4*)Abf, n4x);
  int n4w = (N * K) / 4;
  cvt_w_kernel<<<(n4w + 255) / 256, 256, 0, stream>>>((const int4*)w, (ushort4*)Wbf, n4w);

  dim3 grid(N / 128, M / 128);
  gemm_bt_kernel<<<grid, 256, 0, stream>>>(Abf, Wbf, sc, out, M, N, K);
}